// Round 1
// baseline (504.589 us; speedup 1.0000x reference)
//
#include <hip/hip_runtime.h>
#include <hip/hip_bf16.h>

// SDPA with bias, materializing both output and attention weights.
// B=4, H=8, T=2048, DK=64, all fp32 in/out. bf16 MFMA (16x16x32) inside.
#define TT   2048
#define DKK  64
#define NHH  8
#define NBB  4
#define QB   64
#define KBLK 64
#define NKT  (TT / KBLK)   // 32
#define LDE  72            // padded LDS stride (elements): 144 B = 36 banks -> conflict-free b128
#define SCALE 0.125f       // 1/sqrt(64)

typedef __attribute__((ext_vector_type(4))) float  f32x4;
typedef __attribute__((ext_vector_type(8))) __bf16 bf16x8;
typedef __attribute__((ext_vector_type(4))) __bf16 bf16x4;

__global__ __launch_bounds__(256, 2)
void sdpa_kernel(const float* __restrict__ Qp, const float* __restrict__ Kp,
                 const float* __restrict__ Vp, const float* __restrict__ Bp,
                 float* __restrict__ Op, float* __restrict__ Wp)
{
    __shared__ __bf16 Kl[KBLK * LDE];      // K tile [key][d] bf16 (also Q staging at start)
    __shared__ __bf16 VTl[DKK * LDE];      // V^T tile [d][key] bf16
    __shared__ __bf16 Pl[4][16 * LDE];     // per-wave P [q][key] bf16

    const int tid  = threadIdx.x;
    const int lane = tid & 63;
    const int wv   = tid >> 6;     // wave 0..3 -> q columns wv*16..+15
    const int g    = lane >> 4;    // 0..3
    const int ql   = lane & 15;

    const int qt = blockIdx.x;     // q tile
    const int bh = blockIdx.y;     // b*H + h
    const int h  = bh & (NHH - 1);

    const float* Qb = Qp + (size_t)bh * TT * DKK;
    const float* Kb = Kp + (size_t)bh * TT * DKK;
    const float* Vb = Vp + (size_t)bh * TT * DKK;

    const int q_local = wv * 16 + ql;
    const int q_glob  = qt * QB + q_local;
    const float* biasRow = Bp + ((size_t)h * TT + q_glob) * TT;
    float* Wrow = Wp + ((size_t)bh * TT + q_glob) * TT;

    // ---- stage Q tile (into Kl), extract per-wave Q fragments (B-operand) ----
    {
        const float* Qt = Qb + (size_t)qt * QB * DKK;
        #pragma unroll
        for (int i = 0; i < 4; ++i) {
            int idx = tid + i * 256;
            int row = idx >> 4, c4 = idx & 15;
            f32x4 v = *(const f32x4*)(Qt + row * DKK + c4 * 4);
            bf16x4 b = {(__bf16)v[0], (__bf16)v[1], (__bf16)v[2], (__bf16)v[3]};
            *(bf16x4*)&Kl[row * LDE + c4 * 4] = b;
        }
    }
    __syncthreads();
    // B-frag: lane holds Q[q0w+ql][d = 8g+j (+32)]
    const bf16x8 qfrag0 = *(const bf16x8*)&Kl[q_local * LDE + g * 8];
    const bf16x8 qfrag1 = *(const bf16x8*)&Kl[q_local * LDE + 32 + g * 8];
    __syncthreads();

    float m_run = -1e30f, l_run = 0.0f;

    // ================= phase 1: online softmax stats =================
    for (int kt = 0; kt < NKT; ++kt) {
        const float* Kt = Kb + (size_t)kt * KBLK * DKK;
        #pragma unroll
        for (int i = 0; i < 4; ++i) {
            int idx = tid + i * 256;
            int row = idx >> 4, c4 = idx & 15;
            f32x4 v = *(const f32x4*)(Kt + row * DKK + c4 * 4);
            bf16x4 b = {(__bf16)v[0], (__bf16)v[1], (__bf16)v[2], (__bf16)v[3]};
            *(bf16x4*)&Kl[row * LDE + c4 * 4] = b;
        }
        __syncthreads();

        // S^T = K · Q^T : acc[s][r] = S^T[key = s*16+4g+r][q = q0w+ql]
        f32x4 acc[4] = {};
        #pragma unroll
        for (int s = 0; s < 4; ++s) {
            bf16x8 a0 = *(const bf16x8*)&Kl[(s * 16 + ql) * LDE + g * 8];
            acc[s] = __builtin_amdgcn_mfma_f32_16x16x32_bf16(a0, qfrag0, acc[s], 0, 0, 0);
            bf16x8 a1 = *(const bf16x8*)&Kl[(s * 16 + ql) * LDE + 32 + g * 8];
            acc[s] = __builtin_amdgcn_mfma_f32_16x16x32_bf16(a1, qfrag1, acc[s], 0, 0, 0);
        }
        const float* bp = biasRow + kt * KBLK;
        float tmax = -1e30f;
        #pragma unroll
        for (int s = 0; s < 4; ++s) {
            f32x4 bv = *(const f32x4*)(bp + s * 16 + g * 4);
            acc[s] = acc[s] * SCALE + bv;
            tmax = fmaxf(tmax, fmaxf(fmaxf(acc[s][0], acc[s][1]), fmaxf(acc[s][2], acc[s][3])));
        }
        tmax = fmaxf(tmax, __shfl_xor(tmax, 16));
        tmax = fmaxf(tmax, __shfl_xor(tmax, 32));
        const float m_new = fmaxf(m_run, tmax);
        const float fac = __expf(m_run - m_new);
        float tsum = 0.0f;
        #pragma unroll
        for (int s = 0; s < 4; ++s) {
            tsum += __expf(acc[s][0] - m_new) + __expf(acc[s][1] - m_new)
                  + __expf(acc[s][2] - m_new) + __expf(acc[s][3] - m_new);
        }
        tsum += __shfl_xor(tsum, 16);
        tsum += __shfl_xor(tsum, 32);
        l_run = l_run * fac + tsum;
        m_run = m_new;
        __syncthreads();
    }

    const float inv_l = 1.0f / l_run;
    f32x4 oacc[4] = {};   // O^T[d = m*16+4g+r][q = q0w+ql]

    // ================= phase 2: recompute, write W, accumulate PV ====
    for (int kt = 0; kt < NKT; ++kt) {
        const float* Kt = Kb + (size_t)kt * KBLK * DKK;
        const float* Vt = Vb + (size_t)kt * KBLK * DKK;
        #pragma unroll
        for (int i = 0; i < 4; ++i) {
            int idx = tid + i * 256;
            int row = idx >> 4, c4 = idx & 15;
            f32x4 v = *(const f32x4*)(Kt + row * DKK + c4 * 4);
            bf16x4 b = {(__bf16)v[0], (__bf16)v[1], (__bf16)v[2], (__bf16)v[3]};
            *(bf16x4*)&Kl[row * LDE + c4 * 4] = b;
            f32x4 u = *(const f32x4*)(Vt + row * DKK + c4 * 4);
            VTl[(c4 * 4 + 0) * LDE + row] = (__bf16)u[0];
            VTl[(c4 * 4 + 1) * LDE + row] = (__bf16)u[1];
            VTl[(c4 * 4 + 2) * LDE + row] = (__bf16)u[2];
            VTl[(c4 * 4 + 3) * LDE + row] = (__bf16)u[3];
        }
        __syncthreads();

        f32x4 acc[4] = {};
        #pragma unroll
        for (int s = 0; s < 4; ++s) {
            bf16x8 a0 = *(const bf16x8*)&Kl[(s * 16 + ql) * LDE + g * 8];
            acc[s] = __builtin_amdgcn_mfma_f32_16x16x32_bf16(a0, qfrag0, acc[s], 0, 0, 0);
            bf16x8 a1 = *(const bf16x8*)&Kl[(s * 16 + ql) * LDE + 32 + g * 8];
            acc[s] = __builtin_amdgcn_mfma_f32_16x16x32_bf16(a1, qfrag1, acc[s], 0, 0, 0);
        }
        const float* bp = biasRow + kt * KBLK;
        #pragma unroll
        for (int s = 0; s < 4; ++s) {
            f32x4 bv = *(const f32x4*)(bp + s * 16 + g * 4);
            f32x4 x = acc[s] * SCALE + bv;
            f32x4 wq;
            wq[0] = __expf(x[0] - m_run) * inv_l;
            wq[1] = __expf(x[1] - m_run) * inv_l;
            wq[2] = __expf(x[2] - m_run) * inv_l;
            wq[3] = __expf(x[3] - m_run) * inv_l;
            *(f32x4*)(Wrow + kt * KBLK + s * 16 + g * 4) = wq;     // weights out
            bf16x4 pb = {(__bf16)wq[0], (__bf16)wq[1], (__bf16)wq[2], (__bf16)wq[3]};
            *(bf16x4*)&Pl[wv][ql * LDE + s * 16 + g * 4] = pb;     // P[q][key]
        }
        __syncthreads();

        // O^T += V^T · P^T
        const bf16x8 bp0 = *(const bf16x8*)&Pl[wv][ql * LDE + g * 8];
        const bf16x8 bp1 = *(const bf16x8*)&Pl[wv][ql * LDE + 32 + g * 8];
        #pragma unroll
        for (int m = 0; m < 4; ++m) {
            bf16x8 av0 = *(const bf16x8*)&VTl[(m * 16 + ql) * LDE + g * 8];
            oacc[m] = __builtin_amdgcn_mfma_f32_16x16x32_bf16(av0, bp0, oacc[m], 0, 0, 0);
            bf16x8 av1 = *(const bf16x8*)&VTl[(m * 16 + ql) * LDE + 32 + g * 8];
            oacc[m] = __builtin_amdgcn_mfma_f32_16x16x32_bf16(av1, bp1, oacc[m], 0, 0, 0);
        }
        __syncthreads();
    }

    // ---- store O: oacc[m][r] = O[q_glob][m*16+4g+r] ----
    float* Orow = Op + ((size_t)bh * TT + q_glob) * DKK;
    #pragma unroll
    for (int m = 0; m < 4; ++m) {
        *(f32x4*)(Orow + m * 16 + g * 4) = oacc[m];
    }
}

extern "C" void kernel_launch(void* const* d_in, const int* in_sizes, int n_in,
                              void* d_out, int out_size, void* d_ws, size_t ws_size,
                              hipStream_t stream) {
    const float* Q  = (const float*)d_in[0];
    const float* K  = (const float*)d_in[1];
    const float* V  = (const float*)d_in[2];
    const float* Bs = (const float*)d_in[3];
    float* Out = (float*)d_out;
    float* W   = Out + (size_t)NBB * NHH * TT * DKK;   // weights follow output
    dim3 grid(TT / QB, NBB * NHH);
    sdpa_kernel<<<grid, dim3(256, 1, 1), 0, stream>>>(Q, K, V, Bs, Out, W);
}